// Round 11
// baseline (124.774 us; speedup 1.0000x reference)
//
#include <hip/hip_runtime.h>

// Problem constants: B=8, H=320, W=1024, CH=CW=3, MAXINS=200
#define BATCH   8
#define HW      (320 * 1024)        // 327680 pixels per batch (mult of 4)
#define ELEMS   (HW * 9)            // 2949120 floats per batch
#define MAXINS  200
#define BINS    (MAXINS * 9)        // 1800 global bins per batch
#define LBINS   (MAXINS * 12)       // padded LDS layout: 12 slots/instance
#define NXBLK   160                 // compress x-blocks per batch
#define QPB     512                 // pixel-quads per block (256 thr x 2)
#define NREP_C  3                   // compress reps (diagnostic)
#define NREP_I  4                   // inflate passes (diagnostic)
#define SCALE      2097152.0f
#define INV_SCALE_D (1.1 / 2097152.0)

__device__ __forceinline__ void decode8(int e, int& pix0, int& pix1,
                                        int& j0, int& b) {
    pix0 = e / 9;
    j0   = e - pix0 * 9;
    b    = 9 - j0;
    pix1 = (e + 7) / 9;
}

// ---------------------------------------------------------------------------
// DIAGNOSTIC: R10's quad-pixel compress, 3 identical reps in one dispatch so
// it exceeds the harness fills' ~55us and surfaces in rocprof top-5 with real
// counters. Rep r flushes to table r; only table 0 is consumed downstream.
// ---------------------------------------------------------------------------
__global__ __launch_bounds__(256) void epp_compress_x3(
    const int* __restrict__ inst, const float* __restrict__ src,
    int* __restrict__ compi)
{
    __shared__ int bins[LBINS];
    const int b = blockIdx.y;
    const int* __restrict__ instb = inst + b * HW;
    const float4* __restrict__ srcb = (const float4*)(src + (size_t)b * ELEMS);
    const int q0 = blockIdx.x * QPB;

    for (int rep = 0; rep < NREP_C; ++rep) {
        for (int i = threadIdx.x; i < LBINS; i += 256) bins[i] = 0;
        __syncthreads();

#pragma unroll
        for (int it = 0; it < 2; ++it) {
            const int q = q0 + it * 256 + threadIdx.x;
            const int p = q * 4;
            const int4 ids = *(const int4*)(instb + p);
            int base[4] = {ids.x * 12, ids.y * 12, ids.z * 12, ids.w * 12};

            const float4* s = srcb + (size_t)q * 9;
            float4 f[9];
#pragma unroll
            for (int r = 0; r < 9; ++r) f[r] = s[r];

#pragma unroll
            for (int r = 0; r < 9; ++r) {
                const float v[4] = {f[r].x, f[r].y, f[r].z, f[r].w};
#pragma unroll
                for (int c = 0; c < 4; ++c) {
                    const int i  = 4 * r + c;
                    const int px = i / 9;
                    const int j  = i - px * 9;
                    atomicAdd(&bins[base[px] + j],
                              __float2int_rn(v[c] * SCALE));
                }
            }
        }
        __syncthreads();

        int* __restrict__ cb = compi + (size_t)rep * BATCH * BINS + b * BINS;
        for (int i = threadIdx.x; i < BINS; i += 256) {
            const int id = i / 9, j = i - id * 9;
            atomicAdd(&cb[i], bins[id * 12 + j]);
        }
        __syncthreads();
    }
}

// ---------------------------------------------------------------------------
// DIAGNOSTIC: inflate with 4 gather+store passes (stage LDS once). Passes
// 0..2 write ws scratch, pass 3 writes the real out (last write = validated).
// ---------------------------------------------------------------------------
__global__ __launch_bounds__(256) void epp_inflate_x4(
    const int* __restrict__ inst, const int* __restrict__ compi,
    float* __restrict__ scratch, float* __restrict__ out)
{
    __shared__ float bins[BINS];
    const int b = blockIdx.y;
    const int* __restrict__ cb = compi + b * BINS;   // table 0
    for (int i = threadIdx.x; i < BINS; i += 256) {
        bins[i] = (float)((double)cb[i] * INV_SCALE_D);
    }
    __syncthreads();

    const int total8 = ELEMS / 8;
    const int* __restrict__ instb = inst + b * HW;
    const int stride = gridDim.x * 256;

    for (int rep = 0; rep < NREP_I; ++rep) {
        float* __restrict__ dstb =
            ((rep == NREP_I - 1) ? out : scratch) + (size_t)b * ELEMS;
        float4* __restrict__ outb = (float4*)dstb;

        for (int g = blockIdx.x * 256 + threadIdx.x; g < total8; g += stride) {
            const int e = g * 8;
            int pix0, pix1, j0, cnt8;
            decode8(e, pix0, pix1, j0, cnt8);
            const int id0 = instb[pix0] * 9 + j0;
            const int id1 = instb[pix1] * 9 + j0 - 9;
            float vals[8];
#pragma unroll
            for (int k = 0; k < 8; ++k) {
                int base = (k < cnt8) ? id0 : id1;
                vals[k] = bins[base + k];
            }
            outb[2 * g]     = make_float4(vals[0], vals[1], vals[2], vals[3]);
            outb[2 * g + 1] = make_float4(vals[4], vals[5], vals[6], vals[7]);
        }
    }
}

// ---------------------------------------------------------------------------
// R10 production kernels (fallback if ws is too small for diagnostics).
// ---------------------------------------------------------------------------
__global__ __launch_bounds__(256) void epp_compress(
    const int* __restrict__ inst, const float* __restrict__ src,
    int* __restrict__ compi)
{
    __shared__ int bins[LBINS];
    const int b = blockIdx.y;
    for (int i = threadIdx.x; i < LBINS; i += 256) bins[i] = 0;
    __syncthreads();
    const int* __restrict__ instb = inst + b * HW;
    const float4* __restrict__ srcb = (const float4*)(src + (size_t)b * ELEMS);
    const int q0 = blockIdx.x * QPB;
#pragma unroll
    for (int it = 0; it < 2; ++it) {
        const int q = q0 + it * 256 + threadIdx.x;
        const int p = q * 4;
        const int4 ids = *(const int4*)(instb + p);
        int base[4] = {ids.x * 12, ids.y * 12, ids.z * 12, ids.w * 12};
        const float4* s = srcb + (size_t)q * 9;
        float4 f[9];
#pragma unroll
        for (int r = 0; r < 9; ++r) f[r] = s[r];
#pragma unroll
        for (int r = 0; r < 9; ++r) {
            const float v[4] = {f[r].x, f[r].y, f[r].z, f[r].w};
#pragma unroll
            for (int c = 0; c < 4; ++c) {
                const int i  = 4 * r + c;
                const int px = i / 9;
                const int j  = i - px * 9;
                atomicAdd(&bins[base[px] + j], __float2int_rn(v[c] * SCALE));
            }
        }
    }
    __syncthreads();
    int* __restrict__ cb = compi + b * BINS;
    for (int i = threadIdx.x; i < BINS; i += 256) {
        const int id = i / 9, j = i - id * 9;
        atomicAdd(&cb[i], bins[id * 12 + j]);
    }
}

__global__ __launch_bounds__(256) void epp_inflate(
    const int* __restrict__ inst, const int* __restrict__ compi,
    float* __restrict__ out)
{
    __shared__ float bins[BINS];
    const int b = blockIdx.y;
    const int* __restrict__ cb = compi + b * BINS;
    for (int i = threadIdx.x; i < BINS; i += 256) {
        bins[i] = (float)((double)cb[i] * INV_SCALE_D);
    }
    __syncthreads();
    const int total8 = ELEMS / 8;
    const int* __restrict__ instb = inst + b * HW;
    float4* __restrict__ outb = (float4*)(out + (size_t)b * ELEMS);
    const int stride = gridDim.x * 256;
    for (int g = blockIdx.x * 256 + threadIdx.x; g < total8; g += stride) {
        const int e = g * 8;
        int pix0, pix1, j0, cnt8;
        decode8(e, pix0, pix1, j0, cnt8);
        const int id0 = instb[pix0] * 9 + j0;
        const int id1 = instb[pix1] * 9 + j0 - 9;
        float vals[8];
#pragma unroll
        for (int k = 0; k < 8; ++k) {
            int base = (k < cnt8) ? id0 : id1;
            vals[k] = bins[base + k];
        }
        outb[2 * g]     = make_float4(vals[0], vals[1], vals[2], vals[3]);
        outb[2 * g + 1] = make_float4(vals[4], vals[5], vals[6], vals[7]);
    }
}

extern "C" void kernel_launch(void* const* d_in, const int* in_sizes, int n_in,
                              void* d_out, int out_size, void* d_ws, size_t ws_size,
                              hipStream_t stream) {
    const int*   inst = (const int*)d_in[0];
    const float* src  = (const float*)d_in[1];
    float* out = (float*)d_out;

    const size_t tablesInts = (size_t)NREP_C * BATCH * BINS;       // 43200 ints
    const size_t scratchFl  = (size_t)BATCH * ELEMS;               // 94.37 MB
    const size_t needDiag   = tablesInts * 4 + scratchFl * 4;

    int* compi = (int*)d_ws;

    if (ws_size >= needDiag) {
        float* scratch = (float*)(compi + tablesInts);
        (void)hipMemsetAsync(compi, 0, tablesInts * 4, stream);

        dim3 cgrid(NXBLK, BATCH);
        epp_compress_x3<<<cgrid, 256, 0, stream>>>(inst, src, compi);

        dim3 igrid(512, BATCH);
        epp_inflate_x4<<<igrid, 256, 0, stream>>>(inst, compi, scratch, out);
    } else {
        // Production R10 path.
        (void)hipMemsetAsync(compi, 0, (size_t)BATCH * BINS * 4, stream);
        dim3 cgrid(NXBLK, BATCH);
        epp_compress<<<cgrid, 256, 0, stream>>>(inst, src, compi);
        dim3 igrid(512, BATCH);
        epp_inflate<<<igrid, 256, 0, stream>>>(inst, compi, out);
    }
}

// Round 12
// 50.861 us; speedup vs baseline: 2.4532x; 2.4532x over previous
//
#include <hip/hip_runtime.h>

// Problem constants: B=8, H=320, W=1024, CH=CW=3, MAXINS=200
#define BATCH   8
#define HW      (320 * 1024)        // 327680 pixels per batch (mult of 4)
#define ELEMS   (HW * 9)            // 2949120 floats per batch
#define MAXINS  200
#define BINS    (MAXINS * 9)        // 1800 bins per batch; stride 9 is odd ->
                                    // gcd(9,32)=1 -> full 32-bank spread.
                                    // (R10's stride 12 hit only 8 banks: 33%
                                    // of compress cycles were conflict stalls)
#define NXBLK   160                 // compress x-blocks per batch
#define QPB     512                 // pixel-quads per block (256 thr x 2)
#define SCALE      2097152.0f       // 2^21 fixed-point scale
#define INV_SCALE_D (1.1 / 2097152.0)

// Decode an 8-element group starting at e (inflate path): spans <=2 pixels.
__device__ __forceinline__ void decode8(int e, int& pix0, int& pix1,
                                        int& j0, int& b) {
    pix0 = e / 9;
    j0   = e - pix0 * 9;
    b    = 9 - j0;
    pix1 = (e + 7) / 9;
}

// ---------------------------------------------------------------------------
// Compress, quad-pixel form: each thread-iteration owns 4 aligned pixels =
// 36 floats. All (pixel, j) decomposition is compile-time: one int4 id load,
// 9 aligned float4 loads, 36 ds_add with static j off 4 id*9 bases.
// LDS histogram stride = 9 (compact): full bank spread, identity flush.
// ---------------------------------------------------------------------------
__global__ __launch_bounds__(256) void epp_compress(
    const int* __restrict__ inst, const float* __restrict__ src,
    int* __restrict__ compi)
{
    __shared__ int bins[BINS];
    const int b = blockIdx.y;

    for (int i = threadIdx.x; i < BINS; i += 256) bins[i] = 0;
    __syncthreads();

    const int* __restrict__ instb = inst + b * HW;
    const float4* __restrict__ srcb = (const float4*)(src + (size_t)b * ELEMS);
    const int q0 = blockIdx.x * QPB;

#pragma unroll
    for (int it = 0; it < 2; ++it) {
        const int q = q0 + it * 256 + threadIdx.x;   // pixel-quad index
        const int p = q * 4;                         // first pixel (4-aligned)
        const int4 ids = *(const int4*)(instb + p);  // 16B-aligned id load
        int base[4] = {ids.x * 9, ids.y * 9, ids.z * 9, ids.w * 9};

        const float4* s = srcb + (size_t)q * 9;      // 36 floats, 16B-aligned
        float4 f[9];
#pragma unroll
        for (int r = 0; r < 9; ++r) f[r] = s[r];

#pragma unroll
        for (int r = 0; r < 9; ++r) {
            const float v[4] = {f[r].x, f[r].y, f[r].z, f[r].w};
#pragma unroll
            for (int c = 0; c < 4; ++c) {
                const int i  = 4 * r + c;            // 0..35, static
                const int px = i / 9;                // static
                const int j  = i - px * 9;           // static
                atomicAdd(&bins[base[px] + j],       // ds_add, imm offset j
                          __float2int_rn(v[c] * SCALE));
            }
        }
    }
    __syncthreads();

    // Identity flush: native global int atomics into the per-batch table.
    int* __restrict__ cb = compi + b * BINS;
    for (int i = threadIdx.x; i < BINS; i += 256) {
        atomicAdd(&cb[i], bins[i]);
    }
}

// ---------------------------------------------------------------------------
// Inflate (proven form, ~85% of write peak in R11 diagnostic): stage table
// in LDS converting int->float with 1.1/SCALE folded; decode8 gather;
// coalesced float4 stores.
// ---------------------------------------------------------------------------
__global__ __launch_bounds__(256) void epp_inflate(
    const int* __restrict__ inst, const int* __restrict__ compi,
    float* __restrict__ out)
{
    __shared__ float bins[BINS];
    const int b = blockIdx.y;
    const int* __restrict__ cb = compi + b * BINS;
    for (int i = threadIdx.x; i < BINS; i += 256) {
        bins[i] = (float)((double)cb[i] * INV_SCALE_D);
    }
    __syncthreads();

    const int total8 = ELEMS / 8;
    const int* __restrict__ instb = inst + b * HW;
    float4* __restrict__ outb = (float4*)(out + (size_t)b * ELEMS);
    const int stride = gridDim.x * 256;

    for (int g = blockIdx.x * 256 + threadIdx.x; g < total8; g += stride) {
        const int e = g * 8;
        int pix0, pix1, j0, cnt8;
        decode8(e, pix0, pix1, j0, cnt8);
        const int id0 = instb[pix0] * 9 + j0;
        const int id1 = instb[pix1] * 9 + j0 - 9;
        float vals[8];
#pragma unroll
        for (int k = 0; k < 8; ++k) {
            int base = (k < cnt8) ? id0 : id1;
            vals[k] = bins[base + k];
        }
        outb[2 * g]     = make_float4(vals[0], vals[1], vals[2], vals[3]);
        outb[2 * g + 1] = make_float4(vals[4], vals[5], vals[6], vals[7]);
    }
}

extern "C" void kernel_launch(void* const* d_in, const int* in_sizes, int n_in,
                              void* d_out, int out_size, void* d_ws, size_t ws_size,
                              hipStream_t stream) {
    const int*   inst = (const int*)d_in[0];    // [B,1,H,W] int32
    const float* src  = (const float*)d_in[1];  // [B,H,W,3,3] f32
    float* out = (float*)d_out;                 // [B,H,W,3,3] f32

    const size_t compBytes = (size_t)BATCH * BINS * sizeof(int);   // 57.6 KB
    if (ws_size < compBytes) return;            // ws has always been >= 300MB

    int* compi = (int*)d_ws;

    // Zero the int accumulator every call (graph-safe, 57.6 KB).
    (void)hipMemsetAsync(compi, 0, compBytes, stream);

    dim3 cgrid(NXBLK, BATCH);                   // 1280 blocks, 2 quads/thread
    epp_compress<<<cgrid, 256, 0, stream>>>(inst, src, compi);

    dim3 igrid(512, BATCH);                     // 4096 blocks (proven config)
    epp_inflate<<<igrid, 256, 0, stream>>>(inst, compi, out);
}